// Round 9
// baseline (116.555 us; speedup 1.0000x reference)
//
#include <hip/hip_runtime.h>
#include <hip/hip_bf16.h>

#define NTOK 64
#define CDIM 128
#define SCALE 0.17677669529663688f   // 1/sqrt(32), folded into Wq/bq

typedef __attribute__((ext_vector_type(4))) float  f32x4;
typedef __attribute__((ext_vector_type(8))) short  bf16x8;
typedef __attribute__((ext_vector_type(4))) short  s16x4;

__device__ __forceinline__ unsigned pk2u(float a, float b) {
  union { __hip_bfloat162 h; unsigned u; } c;
  c.h = __float22bfloat162_rn(float2{a, b});
  return c.u;
}
__device__ __forceinline__ s16x4 pk4(f32x4 v) {
  union { unsigned u[2]; s16x4 s; } r;
  r.u[0] = pk2u(v.x, v.y); r.u[1] = pk2u(v.z, v.w);
  return r.s;
}

struct CPack { unsigned p0, p1; };
__device__ __forceinline__ CPack packC(f32x4 v) {
  CPack c; c.p0 = pk2u(v.x, v.y); c.p1 = pk2u(v.z, v.w); return c;
}

// C-layout -> MFMA A/B-frag repack (in-register). Validated R5/R6.
__device__ __forceinline__ bf16x8 gatherFrag(CPack t0, CPack t1, int li, int g) {
  int L0 = ((g & 1) * 2) * 16 + li;
  int L1 = L0 + 16;
  unsigned a0 = __shfl(t0.p0, L0, 64), a1 = __shfl(t0.p1, L0, 64);
  unsigned a2 = __shfl(t0.p0, L1, 64), a3 = __shfl(t0.p1, L1, 64);
  unsigned b0 = __shfl(t1.p0, L0, 64), b1 = __shfl(t1.p1, L0, 64);
  unsigned b2 = __shfl(t1.p0, L1, 64), b3 = __shfl(t1.p1, L1, 64);
  bool hi = (g & 2) != 0;
  union { unsigned u[4]; bf16x8 v; } r;
  r.u[0] = hi ? b0 : a0; r.u[1] = hi ? b1 : a1;
  r.u[2] = hi ? b2 : a2; r.u[3] = hi ? b3 : a3;
  return r.v;
}

// XOR-swizzle within a 256B row: 16B granule, 3 row bits (validated R2)
__device__ __forceinline__ int swz(int row, int cb, int stride) {
  return row * stride + (cb ^ ((row & 7) << 4));
}

__global__ void wconv_kernel(const float* __restrict__ wq, const float* __restrict__ wk,
                             const float* __restrict__ wv, const float* __restrict__ wo,
                             short* __restrict__ wbf) {
  int t = (blockIdx.x * 256 + threadIdx.x) * 4;   // 16 blocks
  f32x4 a = *reinterpret_cast<const f32x4*>(wq + t);
  a.x *= SCALE; a.y *= SCALE; a.z *= SCALE; a.w *= SCALE;   // fold softmax scale into Wq
  f32x4 b = *reinterpret_cast<const f32x4*>(wk + t);
  f32x4 c = *reinterpret_cast<const f32x4*>(wv + t);
  f32x4 d = *reinterpret_cast<const f32x4*>(wo + t);
  *reinterpret_cast<s16x4*>(wbf + t)         = pk4(a);
  *reinterpret_cast<s16x4*>(wbf + 16384 + t) = pk4(b);
  *reinterpret_cast<s16x4*>(wbf + 32768 + t) = pk4(c);
  *reinterpret_cast<s16x4*>(wbf + 49152 + t) = pk4(d);
}

// 1 wave = 1 batch. Zero barriers. Per-wave private 16KB LDS slice holds only
// the staged X (bf16, swizzled); Q/K/V/P/O all live in registers via
// gatherFrag repack. Block = 4 independent waves = 4 batches.
#define SMEM_BYTES 65536

__global__ __launch_bounds__(256, 2) void fused_attn(
    const float* __restrict__ x, const float* __restrict__ ent,
    const short* __restrict__ wbf,
    const float* __restrict__ bq, const float* __restrict__ bk,
    const float* __restrict__ bv, const float* __restrict__ bo,
    const int* __restrict__ beta, float* __restrict__ out)
{
  __shared__ unsigned char sm[SMEM_BYTES];
  const int lane = threadIdx.x & 63;
  const int w    = threadIdx.x >> 6;
  const int g    = lane >> 4;       // 16-lane group 0..3
  const int li   = lane & 15;
  const int b    = blockIdx.x * 4 + w;   // this wave's batch

  unsigned char* X = sm + w * 16384;     // wave-private X slice

  // ---------- stage own batch X (fp32 -> bf16, swizzled), intra-wave only ----------
  {
    const float* xb = x + (size_t)b * (NTOK * CDIM);
    #pragma unroll
    for (int it = 0; it < 32; ++it) {
      int f = (it * 64 + lane) * 4;
      int row = f >> 7, col = f & 127;
      f32x4 v = *reinterpret_cast<const f32x4*>(xb + f);
      *reinterpret_cast<s16x4*>(X + swz(row, col * 2, 256)) = pk4(v);
    }
  }
  // same-wave RAW fence (deterministic; no cross-wave visibility involved)
  asm volatile("s_waitcnt lgkmcnt(0)" ::: "memory");
  __builtin_amdgcn_sched_barrier(0);

  const f32x4 zero4 = {0.f, 0.f, 0.f, 0.f};

  #define LDX(t, kk) (*reinterpret_cast<const bf16x8*>( \
      X + swz((t) * 16 + li, ((kk) * 32 + g * 8) * 2, 256)))

  // gate (per batch, head-independent)
  float4 gv[4];
  {
    const float nb = -(float)beta[0];
    const float* eb = ent + (size_t)b * NTOK;
    #pragma unroll
    for (int mj = 0; mj < 4; ++mj) {
      float4 e = *reinterpret_cast<const float4*>(eb + mj * 16 + g * 4);
      gv[mj].x = nb * e.x; gv[mj].y = nb * e.y; gv[mj].z = nb * e.z; gv[mj].w = nb * e.w;
    }
  }

  bf16x8 of[4][4];   // per-head O fragments [h][ni], consumed by out-proj

  #pragma unroll
  for (int h = 0; h < 4; ++h) {
    // ---------- Q-proj (swapped: Qt = Wq_h * X^T), d in [0,32) of head h ----------
    bf16x8 qf[4], kf[4];
    {
      const short* wm = wbf + (h * 32) * CDIM;
      bf16x8 a0[4], a1[4];
      #pragma unroll
      for (int kk = 0; kk < 4; ++kk) {
        a0[kk] = *reinterpret_cast<const bf16x8*>(wm + li * CDIM + kk * 32 + g * 8);
        a1[kk] = *reinterpret_cast<const bf16x8*>(wm + (16 + li) * CDIM + kk * 32 + g * 8);
      }
      float4 bb0 = *reinterpret_cast<const float4*>(bq + h * 32 + g * 4);
      float4 bb1 = *reinterpret_cast<const float4*>(bq + h * 32 + 16 + g * 4);
      bb0.x *= SCALE; bb0.y *= SCALE; bb0.z *= SCALE; bb0.w *= SCALE;
      bb1.x *= SCALE; bb1.y *= SCALE; bb1.z *= SCALE; bb1.w *= SCALE;
      #pragma unroll
      for (int ni = 0; ni < 4; ++ni) {
        f32x4 c0 = zero4, c1 = zero4;
        #pragma unroll
        for (int kk = 0; kk < 4; ++kk) {
          bf16x8 xr = LDX(ni, kk);
          c0 = __builtin_amdgcn_mfma_f32_16x16x32_bf16(a0[kk], xr, c0, 0, 0, 0);
          c1 = __builtin_amdgcn_mfma_f32_16x16x32_bf16(a1[kk], xr, c1, 0, 0, 0);
        }
        c0.x += bb0.x; c0.y += bb0.y; c0.z += bb0.z; c0.w += bb0.w;
        c1.x += bb1.x; c1.y += bb1.y; c1.z += bb1.z; c1.w += bb1.w;
        qf[ni] = gatherFrag(packC(c0), packC(c1), li, g);
      }
    }
    // ---------- K-proj (same form, no scale) ----------
    {
      const short* wm = wbf + 16384 + (h * 32) * CDIM;
      bf16x8 a0[4], a1[4];
      #pragma unroll
      for (int kk = 0; kk < 4; ++kk) {
        a0[kk] = *reinterpret_cast<const bf16x8*>(wm + li * CDIM + kk * 32 + g * 8);
        a1[kk] = *reinterpret_cast<const bf16x8*>(wm + (16 + li) * CDIM + kk * 32 + g * 8);
      }
      float4 bb0 = *reinterpret_cast<const float4*>(bk + h * 32 + g * 4);
      float4 bb1 = *reinterpret_cast<const float4*>(bk + h * 32 + 16 + g * 4);
      #pragma unroll
      for (int ni = 0; ni < 4; ++ni) {
        f32x4 c0 = zero4, c1 = zero4;
        #pragma unroll
        for (int kk = 0; kk < 4; ++kk) {
          bf16x8 xr = LDX(ni, kk);
          c0 = __builtin_amdgcn_mfma_f32_16x16x32_bf16(a0[kk], xr, c0, 0, 0, 0);
          c1 = __builtin_amdgcn_mfma_f32_16x16x32_bf16(a1[kk], xr, c1, 0, 0, 0);
        }
        c0.x += bb0.x; c0.y += bb0.y; c0.z += bb0.z; c0.w += bb0.w;
        c1.x += bb1.x; c1.y += bb1.y; c1.z += bb1.z; c1.w += bb1.w;
        kf[ni] = gatherFrag(packC(c0), packC(c1), li, g);
      }
    }
    // ---------- V-proj (normal: V = X * Wv_h^T) -> PV A-frags ----------
    bf16x8 vA[2][2];   // [md2 (d tile)][ks (j half)]
    {
      const short* wm = wbf + 32768 + (h * 32) * CDIM;
      bf16x8 b0[4], b1[4];
      #pragma unroll
      for (int kk = 0; kk < 4; ++kk) {
        b0[kk] = *reinterpret_cast<const bf16x8*>(wm + li * CDIM + kk * 32 + g * 8);
        b1[kk] = *reinterpret_cast<const bf16x8*>(wm + (16 + li) * CDIM + kk * 32 + g * 8);
      }
      f32x4 vc[4][2];
      #pragma unroll
      for (int mi = 0; mi < 4; ++mi) { vc[mi][0] = zero4; vc[mi][1] = zero4; }
      #pragma unroll
      for (int mi = 0; mi < 4; ++mi)
        #pragma unroll
        for (int kk = 0; kk < 4; ++kk) {
          bf16x8 xr = LDX(mi, kk);
          vc[mi][0] = __builtin_amdgcn_mfma_f32_16x16x32_bf16(xr, b0[kk], vc[mi][0], 0, 0, 0);
          vc[mi][1] = __builtin_amdgcn_mfma_f32_16x16x32_bf16(xr, b1[kk], vc[mi][1], 0, 0, 0);
        }
      float bb0 = bv[h * 32 + li], bb1 = bv[h * 32 + 16 + li];
      #pragma unroll
      for (int mi = 0; mi < 4; ++mi) {
        vc[mi][0].x += bb0; vc[mi][0].y += bb0; vc[mi][0].z += bb0; vc[mi][0].w += bb0;
        vc[mi][1].x += bb1; vc[mi][1].y += bb1; vc[mi][1].z += bb1; vc[mi][1].w += bb1;
      }
      #pragma unroll
      for (int md2 = 0; md2 < 2; ++md2)
        #pragma unroll
        for (int ks = 0; ks < 2; ++ks)
          vA[md2][ks] = gatherFrag(packC(vc[ks * 2][md2]), packC(vc[ks * 2 + 1][md2]), li, g);
    }
    // ---------- per i-tile fused: scores -> no-max softmax -> PV -> O frag ----------
    #pragma unroll
    for (int ni = 0; ni < 4; ++ni) {
      f32x4 s[4];
      #pragma unroll
      for (int mj = 0; mj < 4; ++mj)
        s[mj] = __builtin_amdgcn_mfma_f32_16x16x32_bf16(kf[mj], qf[ni], zero4, 0, 0, 0);
      float sum = 0.f;
      #pragma unroll
      for (int mj = 0; mj < 4; ++mj) {
        f32x4 v = s[mj];
        v.x = __expf(v.x + gv[mj].x); v.y = __expf(v.y + gv[mj].y);
        v.z = __expf(v.z + gv[mj].z); v.w = __expf(v.w + gv[mj].w);
        s[mj] = v;
        sum += v.x + v.y + v.z + v.w;
      }
      sum += __shfl_xor(sum, 16);
      sum += __shfl_xor(sum, 32);
      float inv = 1.f / (sum + 1e-9f);
      #pragma unroll
      for (int mj = 0; mj < 4; ++mj) {
        s[mj].x *= inv; s[mj].y *= inv; s[mj].z *= inv; s[mj].w *= inv;
      }
      bf16x8 pf0 = gatherFrag(packC(s[0]), packC(s[1]), li, g);
      bf16x8 pf1 = gatherFrag(packC(s[2]), packC(s[3]), li, g);
      f32x4 o0 = zero4, o1 = zero4;
      o0 = __builtin_amdgcn_mfma_f32_16x16x32_bf16(vA[0][0], pf0, o0, 0, 0, 0);
      o0 = __builtin_amdgcn_mfma_f32_16x16x32_bf16(vA[0][1], pf1, o0, 0, 0, 0);
      o1 = __builtin_amdgcn_mfma_f32_16x16x32_bf16(vA[1][0], pf0, o1, 0, 0, 0);
      o1 = __builtin_amdgcn_mfma_f32_16x16x32_bf16(vA[1][1], pf1, o1, 0, 0, 0);
      of[h][ni] = gatherFrag(packC(o0), packC(o1), li, g);
    }
  }

  // ---------- out-proj swapped (Yt = Wo * O^T), streamed per 16-dout tile ----------
  {
    const short* wo_ = wbf + 49152;
    float* yb = out + (size_t)b * (NTOK * CDIM);
    #pragma unroll
    for (int mi = 0; mi < 8; ++mi) {
      bf16x8 wfa[4];
      #pragma unroll
      for (int h = 0; h < 4; ++h)
        wfa[h] = *reinterpret_cast<const bf16x8*>(wo_ + (mi * 16 + li) * CDIM + h * 32 + g * 8);
      f32x4 ay[4];
      #pragma unroll
      for (int ni = 0; ni < 4; ++ni) ay[ni] = zero4;
      #pragma unroll
      for (int ni = 0; ni < 4; ++ni)
        #pragma unroll
        for (int h = 0; h < 4; ++h)
          ay[ni] = __builtin_amdgcn_mfma_f32_16x16x32_bf16(wfa[h], of[h][ni], ay[ni], 0, 0, 0);
      int d0 = mi * 16 + g * 4;
      float4 bo4 = *reinterpret_cast<const float4*>(bo + d0);
      #pragma unroll
      for (int ni = 0; ni < 4; ++ni) {
        int i = ni * 16 + li;
        f32x4 y = ay[ni];
        y.x += bo4.x; y.y += bo4.y; y.z += bo4.z; y.w += bo4.w;
        *reinterpret_cast<f32x4*>(yb + i * CDIM + d0) = y;
      }
    }
  }
  #undef LDX
}

extern "C" void kernel_launch(void* const* d_in, const int* in_sizes, int n_in,
                              void* d_out, int out_size, void* d_ws, size_t ws_size,
                              hipStream_t stream) {
  const float* x    = (const float*)d_in[0];
  const float* ent  = (const float*)d_in[1];
  const float* wq   = (const float*)d_in[2];
  const float* bq   = (const float*)d_in[3];
  const float* wk   = (const float*)d_in[4];
  const float* bk   = (const float*)d_in[5];
  const float* wv   = (const float*)d_in[6];
  const float* bv   = (const float*)d_in[7];
  const float* wo   = (const float*)d_in[8];
  const float* bo   = (const float*)d_in[9];
  const int*   beta = (const int*)d_in[10];

  short* wbf = (short*)d_ws;             // 4 x 128x128 bf16 = 128 KB
  const int B = in_sizes[0] / (NTOK * CDIM);

  wconv_kernel<<<16, 256, 0, stream>>>(wq, wk, wv, wo, wbf);
  fused_attn<<<B / 4, 256, 0, stream>>>(x, ent, wbf, bq, bk, bv, bo, beta, (float*)d_out);
}